// Round 4
// baseline (57.949 us; speedup 1.0000x reference)
//
#include <hip/hip_runtime.h>
#include <hip/hip_bf16.h>

#define K_Q   131072
#define B_N   1024
#define D_DIM 128
#define NCLS  10
#define NC2   20
#define NEG_INF_F (-1e9f)

#define MBLK  512     // k_mfma blocks
#define MW    4       // waves/block
#define MSL   2       // k-slices (of 32) per wave;  MBLK*MW*MSL*32 == K_Q
#define FCH   8       // finalize chunks (MBLK/64)

typedef __attribute__((ext_vector_type(8))) short short8v;  // 8 bf16
typedef __attribute__((ext_vector_type(4))) float vf4;

__device__ __forceinline__ short f2bf(float f) {
    __hip_bfloat16 h = __float2bfloat16(f);
    return *reinterpret_cast<short*>(&h);
}

// ---------------- kernel 0: zero the atomic counters ----------------
__global__ void k_init(int* cnt, int* accCnt) {
    int t = threadIdx.x;
    if (t < NC2) cnt[t] = 0;
    if (t == 0) *accCnt = 0;
}

// ---------------- kernel 1: per-k class code + class counts ----------------
__global__ void k_code(const int* __restrict__ qp, const int* __restrict__ ql,
                       unsigned char* __restrict__ code, int* __restrict__ cnt) {
    __shared__ int lc[NC2];
    int t = threadIdx.x;
    if (t < NC2) lc[t] = 0;
    __syncthreads();
    int idx = blockIdx.x * blockDim.x + t;
    int stride = gridDim.x * blockDim.x;
    for (int k = idx; k < K_Q; k += stride) {
        int p = qp[k];
        int cd = (p == ql[k]) ? p : (p + NCLS);
        code[k] = (unsigned char)cd;
        atomicAdd(&lc[cd], 1);
    }
    __syncthreads();
    if (t < NC2) atomicAdd(&cnt[t], lc[t]);
}

// ---------------- kernel 2: one-hot MFMA scatter-reduce ----------------
// S_pos[c][d] = sum_k {code[k]==c}    * posq[d][k]   (c<10)
// S_neg[c][d] = sum_k {code[k]==c+10} * negq[d][k]
// MFMA 16x16x32 bf16: A row = class (lane&15), B col = d (lane&15),
// k = 8*(lane>>4)+j  (same slot mapping for A and B -> permutation-safe).
__global__ __launch_bounds__(256)
void k_mfma(const float* __restrict__ posq, const float* __restrict__ negq,
            const unsigned char* __restrict__ code, float* __restrict__ partial) {
    const int t    = threadIdx.x;
    const int wave = t >> 6;
    const int lane = t & 63;
    const int bid  = blockIdx.x;
    const int cl   = lane & 15;   // A-row class / B-col d-within-block / C col
    const int g    = lane >> 4;   // k-group

    vf4 accp[8], accn[8];
#pragma unroll
    for (int i = 0; i < 8; ++i) {
        accp[i] = (vf4){0.f, 0.f, 0.f, 0.f};
        accn[i] = (vf4){0.f, 0.f, 0.f, 0.f};
    }

    for (int s = 0; s < MSL; ++s) {
        const int gslice = (bid * MW + wave) * MSL + s;
        const int kl = gslice * 32 + g * 8;     // this lane's 8 consecutive k's

        // one-hot A fragments from code bytes (broadcast within lane-group)
        uint2 cw = *(const uint2*)(code + kl);
        short8v ap, an;
#pragma unroll
        for (int j = 0; j < 8; ++j) {
            unsigned b = (((j < 4) ? cw.x : cw.y) >> (8 * (j & 3))) & 0xffu;
            ap[j] = (b == (unsigned)cl)          ? (short)0x3F80 : (short)0;
            an[j] = (b == (unsigned)(cl + NCLS)) ? (short)0x3F80 : (short)0;
        }

#pragma unroll
        for (int db = 0; db < 8; ++db) {
            const int d = db * 16 + cl;
            const float* pp = posq + (size_t)d * K_Q + kl;
            const float* np = negq + (size_t)d * K_Q + kl;
            float4 p0 = ((const float4*)pp)[0];
            float4 p1 = ((const float4*)pp)[1];
            float4 n0 = ((const float4*)np)[0];
            float4 n1 = ((const float4*)np)[1];
            short8v bp, bn;
            bp[0] = f2bf(p0.x); bp[1] = f2bf(p0.y); bp[2] = f2bf(p0.z); bp[3] = f2bf(p0.w);
            bp[4] = f2bf(p1.x); bp[5] = f2bf(p1.y); bp[6] = f2bf(p1.z); bp[7] = f2bf(p1.w);
            bn[0] = f2bf(n0.x); bn[1] = f2bf(n0.y); bn[2] = f2bf(n0.z); bn[3] = f2bf(n0.w);
            bn[4] = f2bf(n1.x); bn[5] = f2bf(n1.y); bn[6] = f2bf(n1.z); bn[7] = f2bf(n1.w);
            accp[db] = __builtin_amdgcn_mfma_f32_16x16x32_bf16(ap, bp, accp[db], 0, 0, 0);
            accn[db] = __builtin_amdgcn_mfma_f32_16x16x32_bf16(an, bn, accn[db], 0, 0, 0);
        }
    }

    // block-reduce 4 waves' fragments, write partial[bid][j][d]
    __shared__ float red[MW][64][8];
#pragma unroll
    for (int db = 0; db < 8; ++db) {
        *(vf4*)&red[wave][lane][0] = accp[db];
        *(vf4*)&red[wave][lane][4] = accn[db];
        __syncthreads();
        if (wave == 0) {
#pragma unroll
            for (int r = 0; r < 4; ++r) {
                int cls = g * 4 + r;          // C/D row = class
                if (cls < NCLS) {
                    float sp = red[0][lane][r]     + red[1][lane][r]
                             + red[2][lane][r]     + red[3][lane][r];
                    float sn = red[0][lane][4 + r] + red[1][lane][4 + r]
                             + red[2][lane][4 + r] + red[3][lane][4 + r];
                    partial[((size_t)bid * NC2 + cls)        * D_DIM + db * 16 + cl] = sp;
                    partial[((size_t)bid * NC2 + NCLS + cls) * D_DIM + db * 16 + cl] = sn;
                }
            }
        }
        __syncthreads();
    }
}

// ---------------- kernel 3a: sum partials over 64-block chunks ----------------
__global__ void k_fin1(const float* __restrict__ partial, float* __restrict__ ws2) {
    int idx = blockIdx.x * blockDim.x + threadIdx.x;   // 0 .. 8*2560-1
    if (idx >= FCH * NC2 * D_DIM) return;
    int chunk = idx / (NC2 * D_DIM);
    int jd    = idx % (NC2 * D_DIM);
    float s = 0.0f;
    int b0 = chunk * (MBLK / FCH);
#pragma unroll 8
    for (int b = b0; b < b0 + MBLK / FCH; ++b)
        s += partial[(size_t)b * (NC2 * D_DIM) + jd];
    ws2[(size_t)chunk * (NC2 * D_DIM) + jd] = s;
}

// ---------------- kernel 3b: sum chunks -> S[20][128] ----------------
__global__ void k_fin2(const float* __restrict__ ws2, float* __restrict__ S) {
    int jd = blockIdx.x * blockDim.x + threadIdx.x;
    if (jd >= NC2 * D_DIM) return;
    float s = 0.0f;
#pragma unroll
    for (int ch = 0; ch < FCH; ++ch)
        s += ws2[(size_t)ch * (NC2 * D_DIM) + jd];
    S[jd] = s;
}

// ---------------- kernel 4: per-sample loss ----------------
__global__ void k_loss(const float* __restrict__ q, const int* __restrict__ preds,
                       const float* __restrict__ S, const int* __restrict__ cnt,
                       float* __restrict__ out, int* __restrict__ accCnt) {
    const int b = blockIdx.x;
    const int t = threadIdx.x;  // 128 threads
    const int c = preds[b];

    float qv = q[(size_t)b * D_DIM + t];
    float sp = S[c * D_DIM + t];
    float sn = S[(NCLS + c) * D_DIM + t];
    float s0 = qv * qv, s1 = qv * sp, s2 = qv * sn;

#pragma unroll
    for (int off = 32; off; off >>= 1) {
        s0 += __shfl_xor(s0, off);
        s1 += __shfl_xor(s1, off);
        s2 += __shfl_xor(s2, off);
    }
    __shared__ float red[2][3];
    int wave = t >> 6;
    if ((t & 63) == 0) { red[wave][0] = s0; red[wave][1] = s1; red[wave][2] = s2; }
    __syncthreads();
    if (t == 0) {
        float nq  = red[0][0] + red[1][0];
        float dp  = red[0][1] + red[1][1];
        float dn  = red[0][2] + red[1][2];
        float inv = 1.0f / fmaxf(sqrtf(nq), 1e-12f);
        int cp = cnt[c], cn = cnt[NCLS + c];
        float pl = (cp > 0) ? (dp * inv) / (float)(cp > 1 ? cp : 1) : NEG_INF_F;
        float nl = (cn > 0) ? (dn * inv) / (float)(cn > 1 ? cn : 1) : NEG_INF_F;
        float a  = pl / 0.07f;
        float bb = nl / 0.07f;
        float m  = fmaxf(a, bb);
        float loss = m + logf(expf(a - m) + expf(bb - m)) - a;
        out[b] = loss;
        if (a >= bb) atomicAdd(accCnt, 1);  // argmax ties -> index 0
    }
}

// ---------------- kernel 5: accuracy scalar ----------------
__global__ void k_acc(const int* __restrict__ accCnt, float* __restrict__ out) {
    out[B_N] = (float)(*accCnt) * (1.0f / (float)B_N);
}

extern "C" void kernel_launch(void* const* d_in, const int* in_sizes, int n_in,
                              void* d_out, int out_size, void* d_ws, size_t ws_size,
                              hipStream_t stream) {
    const float* q      = (const float*)d_in[0];
    // d_in[1] = k (unused downstream), d_in[2] = labels (unused)
    const int* preds    = (const int*)d_in[3];
    const float* posq   = (const float*)d_in[4];
    const float* negq   = (const float*)d_in[5];
    const int* qlabels  = (const int*)d_in[6];
    const int* qpreds   = (const int*)d_in[7];
    float* out = (float*)d_out;

    char* ws = (char*)d_ws;
    unsigned char* code = (unsigned char*)ws;                 // 131072 B
    int* cnt            = (int*)(ws + 131072);                // 20 ints
    int* accCnt         = (int*)(ws + 131072 + 80);           // 1 int
    float* partial      = (float*)(ws + 131328);              // MBLK*20*128 f32 = 5.24 MB
    float* ws2          = (float*)(ws + 131328 + (size_t)MBLK * NC2 * D_DIM * 4);  // 8*2560 f32
    float* S            = (float*)(ws + 131328 + (size_t)(MBLK + FCH) * NC2 * D_DIM * 4);

    k_init<<<1, 64, 0, stream>>>(cnt, accCnt);
    k_code<<<256, 256, 0, stream>>>(qpreds, qlabels, code, cnt);
    k_mfma<<<MBLK, 256, 0, stream>>>(posq, negq, code, partial);
    k_fin1<<<(FCH * NC2 * D_DIM + 255) / 256, 256, 0, stream>>>(partial, ws2);
    k_fin2<<<(NC2 * D_DIM + 255) / 256, 256, 0, stream>>>(ws2, S);
    k_loss<<<B_N, 128, 0, stream>>>(q, preds, S, cnt, out, accCnt);
    k_acc<<<1, 1, 0, stream>>>(accCnt, out);
}

// Round 5
// 57.315 us; speedup vs baseline: 1.0111x; 1.0111x over previous
//
#include <hip/hip_runtime.h>
#include <hip/hip_bf16.h>

#define K_Q   131072
#define B_N   1024
#define D_DIM 128
#define NCLS  10
#define NC2   20
#define NEG_INF_F (-1e9f)

#define MBLK  512     // k_mfma blocks
#define MW    8       // waves/block (512 threads); MBLK*MW*32 == K_Q
#define FCH   8       // finalize chunks (MBLK/64)

typedef __attribute__((ext_vector_type(8))) short short8v;  // 8 bf16
typedef __attribute__((ext_vector_type(4))) float vf4;

__device__ __forceinline__ short f2bf(float f) {
    __hip_bfloat16 h = __float2bfloat16(f);
    return *reinterpret_cast<short*>(&h);
}

// ---------------- kernel 0: zero the atomic counters ----------------
__global__ void k_init(int* cnt, int* accCnt) {
    int t = threadIdx.x;
    if (t < NC2) cnt[t] = 0;
    if (t == 0) *accCnt = 0;
}

// ---------------- kernel 1: per-k class code + class counts ----------------
__global__ void k_code(const int* __restrict__ qp, const int* __restrict__ ql,
                       unsigned char* __restrict__ code, int* __restrict__ cnt) {
    __shared__ int lc[NC2];
    int t = threadIdx.x;
    if (t < NC2) lc[t] = 0;
    __syncthreads();
    int idx = blockIdx.x * blockDim.x + t;
    int stride = gridDim.x * blockDim.x;
    for (int k = idx; k < K_Q; k += stride) {
        int p = qp[k];
        int cd = (p == ql[k]) ? p : (p + NCLS);
        code[k] = (unsigned char)cd;
        atomicAdd(&lc[cd], 1);
    }
    __syncthreads();
    if (t < NC2) atomicAdd(&cnt[t], lc[t]);
}

// ---------------- kernel 2: one-hot MFMA scatter-reduce ----------------
// S_pos[c][d] = sum_k {code[k]==c}    * posq[d][k]   (c<10)
// S_neg[c][d] = sum_k {code[k]==c+10} * negq[d][k]
// MFMA 16x16x32 bf16: A row = class (lane&15), B col = d (lane&15),
// k-slot = 8*(lane>>4)+j (same mapping for A and B -> permutation-safe).
// 1 slice (32k x 128d x 2 queues) per wave; 8 waves/block; 16 waves/CU.
__global__ __launch_bounds__(512, 4)
void k_mfma(const float* __restrict__ posq, const float* __restrict__ negq,
            const unsigned char* __restrict__ code, float* __restrict__ partial) {
    const int t    = threadIdx.x;
    const int wave = t >> 6;
    const int lane = t & 63;
    const int bid  = blockIdx.x;
    const int cl   = lane & 15;   // A-row class / B-col d-within-block / C col
    const int g    = lane >> 4;   // k-group

    const int kl = (bid * MW + wave) * 32 + g * 8;  // this lane's 8 k's

    // one-hot A fragments from code bytes
    uint2 cw = *(const uint2*)(code + kl);
    short8v ap, an;
    int posAny = 0, negAny = 0;
#pragma unroll
    for (int j = 0; j < 8; ++j) {
        unsigned b = (((j < 4) ? cw.x : cw.y) >> (8 * (j & 3))) & 0xffu;
        ap[j] = (b == (unsigned)cl)          ? (short)0x3F80 : (short)0;
        an[j] = (b == (unsigned)(cl + NCLS)) ? (short)0x3F80 : (short)0;
        posAny |= (b < (unsigned)NCLS);
        negAny |= (b >= (unsigned)NCLS);
    }

    vf4 accp[8], accn[8];
#pragma unroll
    for (int i = 0; i < 8; ++i) {
        accp[i] = (vf4){0.f, 0.f, 0.f, 0.f};
        accn[i] = (vf4){0.f, 0.f, 0.f, 0.f};
    }

#pragma unroll
    for (int db = 0; db < 8; ++db) {
        const int d = db * 16 + cl;
        short8v bp, bn;
        // lane's 8 slots all-neg -> pos fragment multiplies all-zero A rows: skip load
        if (posAny) {
            const float4* pp = (const float4*)(posq + (size_t)d * K_Q + kl);
            float4 p0 = pp[0], p1 = pp[1];
            bp[0] = f2bf(p0.x); bp[1] = f2bf(p0.y); bp[2] = f2bf(p0.z); bp[3] = f2bf(p0.w);
            bp[4] = f2bf(p1.x); bp[5] = f2bf(p1.y); bp[6] = f2bf(p1.z); bp[7] = f2bf(p1.w);
        } else {
#pragma unroll
            for (int j = 0; j < 8; ++j) bp[j] = 0;
        }
        if (negAny) {
            const float4* np = (const float4*)(negq + (size_t)d * K_Q + kl);
            float4 n0 = np[0], n1 = np[1];
            bn[0] = f2bf(n0.x); bn[1] = f2bf(n0.y); bn[2] = f2bf(n0.z); bn[3] = f2bf(n0.w);
            bn[4] = f2bf(n1.x); bn[5] = f2bf(n1.y); bn[6] = f2bf(n1.z); bn[7] = f2bf(n1.w);
        } else {
#pragma unroll
            for (int j = 0; j < 8; ++j) bn[j] = 0;
        }
        accp[db] = __builtin_amdgcn_mfma_f32_16x16x32_bf16(ap, bp, accp[db], 0, 0, 0);
        accn[db] = __builtin_amdgcn_mfma_f32_16x16x32_bf16(an, bn, accn[db], 0, 0, 0);
    }

    // block-reduce 8 waves' fragments; red[w][j][lane] is lane-contiguous
    __shared__ float red[MW][8][64];
#pragma unroll
    for (int db = 0; db < 8; ++db) {
#pragma unroll
        for (int j = 0; j < 4; ++j) {
            red[wave][j][lane]     = accp[db][j];
            red[wave][j + 4][lane] = accn[db][j];
        }
        __syncthreads();
        if (wave == db) {   // rotate writer wave
#pragma unroll
            for (int r = 0; r < 4; ++r) {
                int cls = g * 4 + r;          // C/D row = class
                if (cls < NCLS) {
                    float sp = 0.f, sn = 0.f;
#pragma unroll
                    for (int w = 0; w < MW; ++w) {
                        sp += red[w][r][lane];
                        sn += red[w][r + 4][lane];
                    }
                    partial[((size_t)bid * NC2 + cls)        * D_DIM + db * 16 + cl] = sp;
                    partial[((size_t)bid * NC2 + NCLS + cls) * D_DIM + db * 16 + cl] = sn;
                }
            }
        }
        __syncthreads();
    }
}

// ---------------- kernel 3a: sum partials over 64-block chunks ----------------
__global__ void k_fin1(const float* __restrict__ partial, float* __restrict__ ws2) {
    int idx = blockIdx.x * blockDim.x + threadIdx.x;   // 0 .. 8*2560-1
    if (idx >= FCH * NC2 * D_DIM) return;
    int chunk = idx / (NC2 * D_DIM);
    int jd    = idx % (NC2 * D_DIM);
    float s = 0.0f;
    int b0 = chunk * (MBLK / FCH);
#pragma unroll 8
    for (int b = b0; b < b0 + MBLK / FCH; ++b)
        s += partial[(size_t)b * (NC2 * D_DIM) + jd];
    ws2[(size_t)chunk * (NC2 * D_DIM) + jd] = s;
}

// ---------------- kernel 3b: sum chunks -> S[20][128] ----------------
__global__ void k_fin2(const float* __restrict__ ws2, float* __restrict__ S) {
    int jd = blockIdx.x * blockDim.x + threadIdx.x;
    if (jd >= NC2 * D_DIM) return;
    float s = 0.0f;
#pragma unroll
    for (int ch = 0; ch < FCH; ++ch)
        s += ws2[(size_t)ch * (NC2 * D_DIM) + jd];
    S[jd] = s;
}

// ---------------- kernel 4: per-sample loss ----------------
__global__ void k_loss(const float* __restrict__ q, const int* __restrict__ preds,
                       const float* __restrict__ S, const int* __restrict__ cnt,
                       float* __restrict__ out, int* __restrict__ accCnt) {
    const int b = blockIdx.x;
    const int t = threadIdx.x;  // 128 threads
    const int c = preds[b];

    float qv = q[(size_t)b * D_DIM + t];
    float sp = S[c * D_DIM + t];
    float sn = S[(NCLS + c) * D_DIM + t];
    float s0 = qv * qv, s1 = qv * sp, s2 = qv * sn;

#pragma unroll
    for (int off = 32; off; off >>= 1) {
        s0 += __shfl_xor(s0, off);
        s1 += __shfl_xor(s1, off);
        s2 += __shfl_xor(s2, off);
    }
    __shared__ float red[2][3];
    int wave = t >> 6;
    if ((t & 63) == 0) { red[wave][0] = s0; red[wave][1] = s1; red[wave][2] = s2; }
    __syncthreads();
    if (t == 0) {
        float nq  = red[0][0] + red[1][0];
        float dp  = red[0][1] + red[1][1];
        float dn  = red[0][2] + red[1][2];
        float inv = 1.0f / fmaxf(sqrtf(nq), 1e-12f);
        int cp = cnt[c], cn = cnt[NCLS + c];
        float pl = (cp > 0) ? (dp * inv) / (float)(cp > 1 ? cp : 1) : NEG_INF_F;
        float nl = (cn > 0) ? (dn * inv) / (float)(cn > 1 ? cn : 1) : NEG_INF_F;
        float a  = pl / 0.07f;
        float bb = nl / 0.07f;
        float m  = fmaxf(a, bb);
        float loss = m + logf(expf(a - m) + expf(bb - m)) - a;
        out[b] = loss;
        if (a >= bb) atomicAdd(accCnt, 1);  // argmax ties -> index 0
    }
}

// ---------------- kernel 5: accuracy scalar ----------------
__global__ void k_acc(const int* __restrict__ accCnt, float* __restrict__ out) {
    out[B_N] = (float)(*accCnt) * (1.0f / (float)B_N);
}

extern "C" void kernel_launch(void* const* d_in, const int* in_sizes, int n_in,
                              void* d_out, int out_size, void* d_ws, size_t ws_size,
                              hipStream_t stream) {
    const float* q      = (const float*)d_in[0];
    // d_in[1] = k (unused downstream), d_in[2] = labels (unused)
    const int* preds    = (const int*)d_in[3];
    const float* posq   = (const float*)d_in[4];
    const float* negq   = (const float*)d_in[5];
    const int* qlabels  = (const int*)d_in[6];
    const int* qpreds   = (const int*)d_in[7];
    float* out = (float*)d_out;

    char* ws = (char*)d_ws;
    unsigned char* code = (unsigned char*)ws;                 // 131072 B
    int* cnt            = (int*)(ws + 131072);                // 20 ints
    int* accCnt         = (int*)(ws + 131072 + 80);           // 1 int
    float* partial      = (float*)(ws + 131328);              // MBLK*20*128 f32 = 5.24 MB
    float* ws2          = (float*)(ws + 131328 + (size_t)MBLK * NC2 * D_DIM * 4);
    float* S            = (float*)(ws + 131328 + (size_t)(MBLK + FCH) * NC2 * D_DIM * 4);

    k_init<<<1, 64, 0, stream>>>(cnt, accCnt);
    k_code<<<256, 256, 0, stream>>>(qpreds, qlabels, code, cnt);
    k_mfma<<<MBLK, 512, 0, stream>>>(posq, negq, code, partial);
    k_fin1<<<(FCH * NC2 * D_DIM + 255) / 256, 256, 0, stream>>>(partial, ws2);
    k_fin2<<<(NC2 * D_DIM + 255) / 256, 256, 0, stream>>>(ws2, S);
    k_loss<<<B_N, 128, 0, stream>>>(q, preds, S, cnt, out, accCnt);
    k_acc<<<1, 1, 0, stream>>>(accCnt, out);
}

// Round 6
// 51.668 us; speedup vs baseline: 1.1216x; 1.1093x over previous
//
#include <hip/hip_runtime.h>
#include <hip/hip_bf16.h>

#define K_Q   131072
#define B_N   1024
#define D_DIM 128
#define NCLS  10
#define NC2   20
#define NEG_INF_F (-1e9f)

#define KC    256        // floats per k-chunk
#define RST   260        // LDS row stride in floats (1040 B: 1024 + 16 pad)
#define CB    64         // chunk-blocks per (dtile, queue)
#define NITER 8          // (K_Q/KC)/CB

typedef __attribute__((ext_vector_type(8))) short short8v;  // 8 bf16
typedef __attribute__((ext_vector_type(4))) float vf4;

__device__ __forceinline__ short f2bf(float f) {
    __hip_bfloat16 h = __float2bfloat16(f);
    return *reinterpret_cast<short*>(&h);
}

// async global->LDS, 16 B per lane; g is PER-LANE addr, l is wave-uniform base
__device__ __forceinline__ void gload_lds16(const float* g, float* l) {
    __builtin_amdgcn_global_load_lds(
        (const __attribute__((address_space(1))) unsigned int*)g,
        (__attribute__((address_space(3))) unsigned int*)l,
        16, 0, 0);
}

// ---------------- kernel 0: zero the atomic counters ----------------
__global__ void k_init(int* cnt, int* accCnt) {
    int t = threadIdx.x;
    if (t < NC2) cnt[t] = 0;
    if (t == 0) *accCnt = 0;
}

// ---------------- kernel 1: per-k class code + class counts ----------------
__global__ void k_code(const int* __restrict__ qp, const int* __restrict__ ql,
                       unsigned char* __restrict__ code, int* __restrict__ cnt) {
    __shared__ int lc[NC2];
    int t = threadIdx.x;
    if (t < NC2) lc[t] = 0;
    __syncthreads();
    int idx = blockIdx.x * blockDim.x + t;
    int stride = gridDim.x * blockDim.x;
    for (int k = idx; k < K_Q; k += stride) {
        int p = qp[k];
        int cd = (p == ql[k]) ? p : (p + NCLS);
        code[k] = (unsigned char)cd;
        atomicAdd(&lc[cd], 1);
    }
    __syncthreads();
    if (t < NC2) atomicAdd(&cnt[t], lc[t]);
}

// ---------------- kernel 2: coalesced LDS-staged one-hot MFMA ----------------
// Block = (cb, dtile, queue). 8 waves. Per iter: stage 16 rows x 1KB via
// global_load_lds (contiguous per instr), double-buffered; wave w = k-step w:
// builds one-hot A from codes, reads B fragment from LDS, 1 MFMA.
__global__ __launch_bounds__(512, 8)
void k_mfma(const float* __restrict__ posq, const float* __restrict__ negq,
            const unsigned char* __restrict__ code, float* __restrict__ partial) {
    __shared__ __align__(16) float lds[2][16 * RST];   // 2 x 16.6 KB
    const int t    = threadIdx.x;
    const int wave = t >> 6;
    const int lane = t & 63;
    const int cl   = lane & 15;   // A row class / B col d / C col
    const int g    = lane >> 4;   // k-group
    const int cb   = blockIdx.x;
    const int dt   = blockIdx.y;
    const int q    = blockIdx.z;
    const float* queue = q ? negq : posq;
    const unsigned tgt = (unsigned)(cl + q * NCLS);   // code byte this row matches

    const size_t rowg = (size_t)(dt * 16 + 2 * wave) * K_Q;  // my 2 staging rows

    vf4 acc = (vf4){0.f, 0.f, 0.f, 0.f};

    // prologue: stage chunk 0 into buf 0
    {
        const float* g0 = queue + rowg + (size_t)cb * KC;
        gload_lds16(g0 + lane * 4,        &lds[0][(2 * wave) * RST]);
        gload_lds16(g0 + K_Q + lane * 4,  &lds[0][(2 * wave + 1) * RST]);
    }
    __syncthreads();

    int cur = 0;
    for (int it = 0; it < NITER; ++it) {
        const int kbase = (it * CB + cb) * KC;
        if (it + 1 < NITER) {   // async prefetch next chunk into other buffer
            const float* g0 = queue + rowg + (size_t)((it + 1) * CB + cb) * KC;
            gload_lds16(g0 + lane * 4,       &lds[cur ^ 1][(2 * wave) * RST]);
            gload_lds16(g0 + K_Q + lane * 4, &lds[cur ^ 1][(2 * wave + 1) * RST]);
        }

        // one-hot A for k-step = wave
        uint2 cw = *(const uint2*)(code + kbase + wave * 32 + g * 8);
        short8v a;
#pragma unroll
        for (int j = 0; j < 8; ++j) {
            unsigned b = (((j < 4) ? cw.x : cw.y) >> (8 * (j & 3))) & 0xffu;
            a[j] = (b == tgt) ? (short)0x3F80 : (short)0;
        }

        // B fragment from LDS: row cl, k = wave*32 + g*8 .. +8
        const float* row = &lds[cur][cl * RST + wave * 32 + g * 8];
        float4 f0 = *(const float4*)(row);
        float4 f1 = *(const float4*)(row + 4);
        short8v b;
        b[0] = f2bf(f0.x); b[1] = f2bf(f0.y); b[2] = f2bf(f0.z); b[3] = f2bf(f0.w);
        b[4] = f2bf(f1.x); b[5] = f2bf(f1.y); b[6] = f2bf(f1.z); b[7] = f2bf(f1.w);

        acc = __builtin_amdgcn_mfma_f32_16x16x32_bf16(a, b, acc, 0, 0, 0);

        __syncthreads();   // drains vmcnt (next buf landed) + lgkm, then barrier
        cur ^= 1;
    }

    // epilogue: sum 8 waves' acc tiles, write partial[blk][cls][16]
    float* red = &lds[0][0];
    *(vf4*)&red[(wave * 64 + lane) * 4] = acc;
    __syncthreads();
    if (wave == 0) {
        vf4 s = (vf4){0.f, 0.f, 0.f, 0.f};
#pragma unroll
        for (int w = 0; w < 8; ++w) {
            vf4 v = *(vf4*)&red[(w * 64 + lane) * 4];
            s[0] += v[0]; s[1] += v[1]; s[2] += v[2]; s[3] += v[3];
        }
        const int blk = (q * 8 + dt) * CB + cb;
#pragma unroll
        for (int j = 0; j < 4; ++j) {
            int cls = g * 4 + j;   // C/D row
            if (cls < NCLS)
                partial[(size_t)blk * (NCLS * 16) + cls * 16 + cl] = s[j];
        }
    }
}

// ---------------- kernel 3: sum partials -> S[20][128] ----------------
__global__ void k_fin(const float* __restrict__ partial, float* __restrict__ S) {
    int idx = blockIdx.x * blockDim.x + threadIdx.x;  // 0..2559
    if (idx >= NC2 * D_DIM) return;
    int j = idx / D_DIM, d = idx % D_DIM;
    int q = j / NCLS, cls = j % NCLS, dt = d / 16, c16 = d & 15;
    const float* p = partial + (size_t)((q * 8 + dt) * CB) * (NCLS * 16) + cls * 16 + c16;
    float s = 0.0f;
#pragma unroll 8
    for (int cb = 0; cb < CB; ++cb) s += p[(size_t)cb * (NCLS * 16)];
    S[idx] = s;   // S[j][d]: j<10 pos class j, j>=10 neg class j-10
}

// ---------------- kernel 4: per-sample loss ----------------
__global__ void k_loss(const float* __restrict__ q, const int* __restrict__ preds,
                       const float* __restrict__ S, const int* __restrict__ cnt,
                       float* __restrict__ out, int* __restrict__ accCnt) {
    const int b = blockIdx.x;
    const int t = threadIdx.x;  // 128 threads
    const int c = preds[b];

    float qv = q[(size_t)b * D_DIM + t];
    float sp = S[c * D_DIM + t];
    float sn = S[(NCLS + c) * D_DIM + t];
    float s0 = qv * qv, s1 = qv * sp, s2 = qv * sn;

#pragma unroll
    for (int off = 32; off; off >>= 1) {
        s0 += __shfl_xor(s0, off);
        s1 += __shfl_xor(s1, off);
        s2 += __shfl_xor(s2, off);
    }
    __shared__ float red[2][3];
    int wave = t >> 6;
    if ((t & 63) == 0) { red[wave][0] = s0; red[wave][1] = s1; red[wave][2] = s2; }
    __syncthreads();
    if (t == 0) {
        float nq  = red[0][0] + red[1][0];
        float dp  = red[0][1] + red[1][1];
        float dn  = red[0][2] + red[1][2];
        float inv = 1.0f / fmaxf(sqrtf(nq), 1e-12f);
        int cp = cnt[c], cn = cnt[NCLS + c];
        float pl = (cp > 0) ? (dp * inv) / (float)(cp > 1 ? cp : 1) : NEG_INF_F;
        float nl = (cn > 0) ? (dn * inv) / (float)(cn > 1 ? cn : 1) : NEG_INF_F;
        float a  = pl / 0.07f;
        float bb = nl / 0.07f;
        float m  = fmaxf(a, bb);
        float loss = m + logf(expf(a - m) + expf(bb - m)) - a;
        out[b] = loss;
        if (a >= bb) atomicAdd(accCnt, 1);  // argmax ties -> index 0
    }
}

// ---------------- kernel 5: accuracy scalar ----------------
__global__ void k_acc(const int* __restrict__ accCnt, float* __restrict__ out) {
    out[B_N] = (float)(*accCnt) * (1.0f / (float)B_N);
}

extern "C" void kernel_launch(void* const* d_in, const int* in_sizes, int n_in,
                              void* d_out, int out_size, void* d_ws, size_t ws_size,
                              hipStream_t stream) {
    const float* q      = (const float*)d_in[0];
    // d_in[1] = k (unused downstream), d_in[2] = labels (unused)
    const int* preds    = (const int*)d_in[3];
    const float* posq   = (const float*)d_in[4];
    const float* negq   = (const float*)d_in[5];
    const int* qlabels  = (const int*)d_in[6];
    const int* qpreds   = (const int*)d_in[7];
    float* out = (float*)d_out;

    char* ws = (char*)d_ws;
    unsigned char* code = (unsigned char*)ws;           // 131072 B
    int* cnt            = (int*)(ws + 131072);          // 20 ints
    int* accCnt         = (int*)(ws + 131072 + 80);     // 1 int
    float* partial      = (float*)(ws + 131328);        // 1024 blk * 160 f32 = 655 KB
    float* S            = (float*)(ws + 131328 + 1024 * NCLS * 16 * 4);

    k_init<<<1, 64, 0, stream>>>(cnt, accCnt);
    k_code<<<256, 256, 0, stream>>>(qpreds, qlabels, code, cnt);
    k_mfma<<<dim3(CB, 8, 2), 512, 0, stream>>>(posq, negq, code, partial);
    k_fin<<<(NC2 * D_DIM + 255) / 256, 256, 0, stream>>>(partial, S);
    k_loss<<<B_N, 128, 0, stream>>>(q, preds, S, cnt, out, accCnt);
    k_acc<<<1, 1, 0, stream>>>(accCnt, out);
}